// Round 5
// baseline (359.634 us; speedup 1.0000x reference)
//
#include <hip/hip_runtime.h>
#include <stdint.h>

#define G  128
#define TT 96
#define NB 2
#define NC 4
#define CS (TT * TT * TT)

typedef float f32x4 __attribute__((ext_vector_type(4)));
typedef float f32x2 __attribute__((ext_vector_type(2)));
typedef _Float16 f16x8 __attribute__((ext_vector_type(8)));
// 8-byte-aligned view for pair loads at odd-voxel offsets
typedef _Float16 f16x8u __attribute__((ext_vector_type(8), aligned(8)));

// ---------- MODE 1 prepass: [B,C,z,y,x] fp32 -> channels-last fp16 (8B/voxel)
__global__ __launch_bounds__(256) void tmpl_repack_f16(
        const float* __restrict__ tmpl, f16x8* __restrict__ out) {
    const int NP = NB * (CS / 2);   // voxel pairs
    int idx = blockIdx.x * 256 + threadIdx.x;
    if (idx >= NP) return;
    int b  = idx / (CS / 2);
    int s2 = idx - b * (CS / 2);
    const float* base = tmpl + (size_t)b * NC * CS + (size_t)s2 * 2;
    f16x8 o;
#pragma unroll
    for (int c = 0; c < NC; ++c) {
        f32x2 v = *(const f32x2*)(base + (size_t)c * CS);   // 8B coalesced
        o[c]     = (_Float16)v.x;
        o[4 + c] = (_Float16)v.y;
    }
    out[idx] = o;
}

// ---------- MODE 2 prepass: 64B record per (z,y,x) = all 8 trilinear corners
// record quads: q0=(z,y | x,x1)  q1=(z,y1)  q2=(z1,y)  q3=(z1,y1); each quad
// is {c0..c3 @ x, c0..c3 @ x1} fp16 (matches v00/v01/v10/v11 consumption).
// One sample gather = ONE 64B cache line.
__global__ __launch_bounds__(256) void tmpl_repack_rec64(
        const float* __restrict__ tmpl, f16x8* __restrict__ out) {
    const int NV = NB * CS;
    int idx = blockIdx.x * 256 + threadIdx.x;
    if (idx >= NV) return;
    int b = idx / CS;
    int s = idx - b * CS;
    int x = s % TT;
    int t = s / TT;
    int y = t % TT;
    int z = t / TT;
    int x1 = min(x + 1, TT - 1);
    int y1 = min(y + 1, TT - 1);
    int z1 = min(z + 1, TT - 1);
    const float* tb = tmpl + (size_t)b * NC * CS;
    int zz[2] = {z, z1};
    int yy[2] = {y, y1};
    f16x8* dst = out + (size_t)idx * 4;
#pragma unroll
    for (int dz = 0; dz < 2; ++dz) {
#pragma unroll
        for (int dy = 0; dy < 2; ++dy) {
            size_t p0 = ((size_t)zz[dz] * TT + yy[dy]) * TT;
            f16x8 o;
#pragma unroll
            for (int c = 0; c < NC; ++c) {
                o[c]     = (_Float16)tb[(size_t)c * CS + p0 + x];   // coalesced in x
                o[4 + c] = (_Float16)tb[(size_t)c * CS + p0 + x1];  // L1-hit overlap
            }
            dst[dz * 2 + dy] = o;   // 4x 16B stores, consecutive
        }
    }
}

// One block = tile of 32(d) x 32(w) at fixed (b, h).
// LDS [c][i=w][j=d], row stride 36. Stage 2 overwrites deform with tanh in place.
// Stage 3: 4 d-consecutive points per thread; MODE selects template layout:
//   2: 64B record  -> 1 cache line / sample (4x dwordx4 same line)
//   1: 8B fp16 voxel -> 4 lines / sample
//   0: raw fp32     -> 32 scalar gathers / sample
template <int MODE>
__global__ __launch_bounds__(256, 4) void fused_sample_kernel(
        const float* __restrict__ grids,
        const float* __restrict__ deform,
        const float* __restrict__ corr,
        const f16x8* __restrict__ tmpl_pk,    // MODE 1/2 packed base
        const float* __restrict__ tmpl_raw,   // MODE 0
        float* __restrict__ out2,
        float* __restrict__ defp) {
    __shared__ float lds[3][32][36];    // [c][i=w][j=d]

    int blk = blockIdx.x;
    int wt = blk & 3;
    int dt = (blk >> 2) & 3;
    int h  = (blk >> 4) & 127;
    int b  = blk >> 11;
    int w0 = wt << 5, d0 = dt << 5;
    int tid = threadIdx.x;

    // ---- stage 1: deformation -> lds[c][i][j4..j4+3]
    for (int idx = tid; idx < 768; idx += 256) {   // 3c * 32i * 8 quads
        int c   = idx >> 8;
        int rem = idx & 255;
        int i   = rem >> 3;
        int j4  = (rem & 7) << 2;
        size_t off = ((((size_t)b * 3 + c) * G + (w0 + i)) * G + h) * G + (d0 + j4);
        f32x4 v = __builtin_nontemporal_load((const f32x4*)(deform + off));
        *(f32x4*)&lds[c][i][j4] = v;
    }
    __syncthreads();

    // ---- stage 2: grids -> field in-place; defp pass-through write
    for (int idx = tid; idx < 768; idx += 256) {   // 32 rows * 24 float4-chunks
        int j = idx / 24;
        int t = idx - j * 24;
        size_t off = (((((size_t)b * G + (d0 + j)) * G + h) * G + w0) * 3) + (size_t)t * 4;
        f32x4 gv = __builtin_nontemporal_load((const f32x4*)(grids + off));
        float dv[4];
#pragma unroll
        for (int k = 0; k < 4; ++k) {
            int e = t * 4 + k;
            int i = e / 3;
            int c = e - 3 * i;
            float d = lds[c][i][j];
            dv[k] = d;                              // exact pass-through
            lds[c][i][j] = tanhf(gv[k] + d);        // same slot, same thread
        }
        __builtin_nontemporal_store(*(f32x4*)dv, (f32x4*)(defp + off));
    }
    __syncthreads();

    // ---- stage 3: 4 d-consecutive points per thread
    const float SC = 0.5f * (TT - 1);
    {
        int i  = tid >> 3;          // w offset
        int j4 = (tid & 7) << 2;    // d offset (4 consecutive)

        f32x4 fx = *(const f32x4*)&lds[0][i][j4];
        f32x4 fy = *(const f32x4*)&lds[1][i][j4];
        f32x4 fz = *(const f32x4*)&lds[2][i][j4];

        float wx[4], wy[4], wz[4];
        int base[4];
#pragma unroll
        for (int k = 0; k < 4; ++k) {
            float ix = (fx[k] + 1.0f) * SC;
            float iy = (fy[k] + 1.0f) * SC;
            float iz = (fz[k] + 1.0f) * SC;
            // tanh in [-1,1] => coords in [0,95]; clamp base to [0,94] and
            // recompute fraction: exactly matches ref clip semantics.
            int x0 = min(max((int)floorf(ix), 0), TT - 2);
            int y0 = min(max((int)floorf(iy), 0), TT - 2);
            int z0 = min(max((int)floorf(iz), 0), TT - 2);
            wx[k] = ix - (float)x0;
            wy[k] = iy - (float)y0;
            wz[k] = iz - (float)z0;
            base[k] = (z0 * TT + y0) * TT + x0;
        }

        float r[4][4];   // [k][c]
        if (MODE >= 1) {
            f16x8 v00[4], v01[4], v10[4], v11[4];
            if (MODE == 2) {
                const char* tb64 = (const char*)tmpl_pk + (size_t)b * ((size_t)CS * 64);
#pragma unroll
                for (int k = 0; k < 4; ++k) {
                    const f16x8* rec = (const f16x8*)(tb64 + (size_t)base[k] * 64);
                    v00[k] = rec[0];   // (z,y)   — all 4 loads hit ONE 64B line
                    v01[k] = rec[1];   // (z,y+1)
                    v10[k] = rec[2];   // (z+1,y)
                    v11[k] = rec[3];   // (z+1,y+1)
                }
            } else {
                const char* tb16 = (const char*)tmpl_pk + (size_t)b * ((size_t)CS * 8);
#pragma unroll
                for (int k = 0; k < 4; ++k) {
                    v00[k] = *(const f16x8u*)(tb16 + ((size_t)base[k]) * 8);
                    v01[k] = *(const f16x8u*)(tb16 + ((size_t)(base[k] + TT)) * 8);
                    v10[k] = *(const f16x8u*)(tb16 + ((size_t)(base[k] + TT * TT)) * 8);
                    v11[k] = *(const f16x8u*)(tb16 + ((size_t)(base[k] + TT * TT + TT)) * 8);
                }
            }
#pragma unroll
            for (int k = 0; k < 4; ++k) {
                float mx = 1.0f - wx[k], my = 1.0f - wy[k], mz = 1.0f - wz[k];
                float a00 = my * mz, a01 = wy[k] * mz;
                float a10 = my * wz[k], a11 = wy[k] * wz[k];
#pragma unroll
                for (int c = 0; c < NC; ++c) {
                    float t00 = (float)v00[k][c] * mx + (float)v00[k][4 + c] * wx[k];
                    float t01 = (float)v01[k][c] * mx + (float)v01[k][4 + c] * wx[k];
                    float t10 = (float)v10[k][c] * mx + (float)v10[k][4 + c] * wx[k];
                    float t11 = (float)v11[k][c] * mx + (float)v11[k][4 + c] * wx[k];
                    r[k][c] = t00 * a00 + t01 * a01 + t10 * a10 + t11 * a11;
                }
            }
        } else {
#pragma unroll
            for (int k = 0; k < 4; ++k) {
                float mx = 1.0f - wx[k], my = 1.0f - wy[k], mz = 1.0f - wz[k];
                float w000 = mx * my * mz, w001 = wx[k] * my * mz;
                float w010 = mx * wy[k] * mz, w011 = wx[k] * wy[k] * mz;
                float w100 = mx * my * wz[k], w101 = wx[k] * my * wz[k];
                float w110 = mx * wy[k] * wz[k], w111 = wx[k] * wy[k] * wz[k];
                size_t i000 = (size_t)base[k];
                size_t i001 = i000 + 1;
                size_t i010 = i000 + TT;
                size_t i011 = i010 + 1;
                size_t i100 = i000 + TT * TT;
                size_t i101 = i100 + 1;
                size_t i110 = i100 + TT;
                size_t i111 = i110 + 1;
#pragma unroll
                for (int c = 0; c < NC; ++c) {
                    const float* tb = tmpl_raw + ((size_t)b * NC + c) * CS;
                    r[k][c] = tb[i000]*w000 + tb[i001]*w001 + tb[i010]*w010 + tb[i011]*w011
                            + tb[i100]*w100 + tb[i101]*w101 + tb[i110]*w110 + tb[i111]*w111;
                }
            }
        }

        int w = w0 + i, d = d0 + j4;
        size_t obase = ((((size_t)b * NC) * (size_t)G + w) * G + h) * G + d;
        const size_t cstride = (size_t)G * G * G;
#pragma unroll
        for (int c = 0; c < NC; ++c) {
            f32x4 cv = __builtin_nontemporal_load((const f32x4*)(corr + obase + c * cstride));
            f32x4 ov;
            ov.x = r[0][c] + cv.x;
            ov.y = r[1][c] + cv.y;
            ov.z = r[2][c] + cv.z;
            ov.w = r[3][c] + cv.w;
            __builtin_nontemporal_store(ov, (f32x4*)(out2 + obase + c * cstride));
        }
    }
}

extern "C" void kernel_launch(void* const* d_in, const int* in_sizes, int n_in,
                              void* d_out, int out_size, void* d_ws, size_t ws_size,
                              hipStream_t stream) {
    const float* grids  = (const float*)d_in[0];
    const float* deform = (const float*)d_in[1];
    const float* corr   = (const float*)d_in[2];
    const float* tmpl   = (const float*)d_in[3];
    float* out2 = (float*)d_out;
    float* defp = out2 + (size_t)NB * NC * G * G * G;   // outputs concatenated flat
    f16x8* tmpl_pk = (f16x8*)d_ws;

    const size_t ws2 = (size_t)NB * CS * 64;   // 113.2 MB: 64B records
    const size_t ws1 = (size_t)NB * CS * 8;    // 14.2 MB: fp16 voxels

    int nblk = NB * G * 16;   // (b,h) * 4 w-tiles * 4 d-tiles = 4096 blocks

    if (ws_size >= ws2) {
        int nv = NB * CS;
        tmpl_repack_rec64<<<(nv + 255) / 256, 256, 0, stream>>>(tmpl, tmpl_pk);
        fused_sample_kernel<2><<<nblk, 256, 0, stream>>>(
            grids, deform, corr, tmpl_pk, tmpl, out2, defp);
    } else if (ws_size >= ws1) {
        int np = NB * (CS / 2);
        tmpl_repack_f16<<<(np + 255) / 256, 256, 0, stream>>>(tmpl, tmpl_pk);
        fused_sample_kernel<1><<<nblk, 256, 0, stream>>>(
            grids, deform, corr, tmpl_pk, tmpl, out2, defp);
    } else {
        fused_sample_kernel<0><<<nblk, 256, 0, stream>>>(
            grids, deform, corr, tmpl_pk, tmpl, out2, defp);
    }
}